// Round 2
// baseline (166.321 us; speedup 1.0000x reference)
//
#include <hip/hip_runtime.h>
#include <hip/hip_bf16.h>

#define VOCAB 100000
#define EMBED 64
#define SENT  20
#define MEM   50
#define BATCH 32
#define HOPS  3

__device__ __forceinline__ float bfr(unsigned short x) {
    union { unsigned int u; float f; } cv;
    cv.u = ((unsigned int)x) << 16;
    return cv.f;
}

// Runtime dtype probe: enc row 19 (last) is exactly 1.0 everywhere.
// bf16 storage: dword 639 packs elements 1278,1279 = (1.0bf,1.0bf) = 0x3F803F80.
// f32 storage: dword 639 = bits of enc[9][63] ~= 0.9508 = 0x3F73xxxx.
__device__ __forceinline__ bool is_bf16(const void* enc) {
    return ((const unsigned int*)enc)[639] == 0x3F803F80u;
}

__device__ __forceinline__ float loadT(const void* p, size_t idx, bool bf) {
    return bf ? bfr(((const unsigned short*)p)[idx]) : ((const float*)p)[idx];
}

// u[b*64+e] = sum_s A[queries[b,s]][e] * enc[s][e]
__global__ void k_query(const int* __restrict__ queries,
                        const void* __restrict__ A,
                        const void* __restrict__ enc,
                        float* __restrict__ u)
{
    bool bf = is_bf16(enc);
    int b = blockIdx.x, e = threadIdx.x;
    int w = (e < SENT) ? queries[b * SENT + e] : 0;
    float acc = 0.f;
#pragma unroll
    for (int s = 0; s < SENT; ++s) {
        int ws = __shfl(w, s, 64);
        acc += loadT(A, (size_t)ws * EMBED + e, bf) * loadT(enc, s * EMBED + e, bf);
    }
    u[b * EMBED + e] = acc;
}

// Per (b,mm): m_e = sum_s Tin[w_s][e]*enc[s][e]; c_e = sum_s Tc[w_s][e]*enc[s][e]
// dotted[b,mm] = sum_e m_e * u[b][e];  c_ws[(b*MEM+mm)*64+e] = c_e
// Tin/Tc are given as base pointer + ELEMENT offset (dtype-scaled on device).
__global__ void k_hop1(const int* __restrict__ stories,
                       const void* __restrict__ Abase,
                       const void* __restrict__ Cbase,
                       size_t tin_off, size_t tc_off, int tin_is_A,
                       const void* __restrict__ enc,
                       const float* __restrict__ u,
                       float* __restrict__ c_ws,
                       float* __restrict__ dotted)
{
    bool bf = is_bf16(enc);
    const void* Tin = tin_is_A ? Abase : Cbase;
    size_t toff = tin_is_A ? 0 : tin_off;

    int bm = blockIdx.x;           // b*MEM + mm
    int b  = bm / MEM;
    int e  = threadIdx.x;
    int w  = (e < SENT) ? stories[bm * SENT + e] : 0;
    float macc = 0.f, cacc = 0.f;
#pragma unroll
    for (int s = 0; s < SENT; ++s) {
        int ws = __shfl(w, s, 64);
        float en = loadT(enc, s * EMBED + e, bf);
        macc += loadT(Tin,   toff  + (size_t)ws * EMBED + e, bf) * en;
        cacc += loadT(Cbase, tc_off + (size_t)ws * EMBED + e, bf) * en;
    }
    c_ws[bm * EMBED + e] = cacc;
    float d = macc * u[b * EMBED + e];
#pragma unroll
    for (int off = 32; off > 0; off >>= 1) d += __shfl_down(d, off, 64);
    if (e == 0) dotted[bm] = d;
}

// softmax over MEM, o_e = sum_mm probs[mm]*c[mm][e], u += o
__global__ void k_hop2(const float* __restrict__ dotted,
                       const float* __restrict__ c_ws,
                       float* __restrict__ u)
{
    int b = blockIdx.x, e = threadIdx.x;
    __shared__ float probs[MEM];
    float x = (e < MEM) ? dotted[b * MEM + e] : -3.4e38f;
    float mx = x;
#pragma unroll
    for (int off = 32; off > 0; off >>= 1) mx = fmaxf(mx, __shfl_xor(mx, off, 64));
    float ex = (e < MEM) ? __expf(x - mx) : 0.f;
    float sm = ex;
#pragma unroll
    for (int off = 32; off > 0; off >>= 1) sm += __shfl_xor(sm, off, 64);
    if (e < MEM) probs[e] = ex / sm;
    __syncthreads();
    float o = 0.f;
#pragma unroll
    for (int mm = 0; mm < MEM; ++mm)
        o += probs[mm] * c_ws[(b * MEM + mm) * EMBED + e];
    u[b * EMBED + e] += o;
}

// out[b*V+v] = sum_e u[b][e] * C[2][v][e]
__global__ __launch_bounds__(256) void k_out(const float* __restrict__ u,
                                             const void* __restrict__ Cbase,
                                             const void* __restrict__ enc,
                                             void* __restrict__ out)
{
    bool bf = is_bf16(enc);
    const size_t c2_off = (size_t)2 * VOCAB * EMBED;   // element offset of C[2]
    __shared__ __align__(16) float su[BATCH * EMBED];
    for (int i = threadIdx.x; i < BATCH * EMBED; i += 256) su[i] = u[i];
    __syncthreads();
    int v = blockIdx.x * 256 + threadIdx.x;
    if (v >= VOCAB) return;

    float row[EMBED];
    if (bf) {
        const uint4* rp = (const uint4*)((const unsigned short*)Cbase + c2_off + (size_t)v * EMBED);
#pragma unroll
        for (int i = 0; i < 8; ++i) {
            uint4 r = rp[i];
            row[i*8 + 0] = bfr((unsigned short)(r.x & 0xffff));
            row[i*8 + 1] = bfr((unsigned short)(r.x >> 16));
            row[i*8 + 2] = bfr((unsigned short)(r.y & 0xffff));
            row[i*8 + 3] = bfr((unsigned short)(r.y >> 16));
            row[i*8 + 4] = bfr((unsigned short)(r.z & 0xffff));
            row[i*8 + 5] = bfr((unsigned short)(r.z >> 16));
            row[i*8 + 6] = bfr((unsigned short)(r.w & 0xffff));
            row[i*8 + 7] = bfr((unsigned short)(r.w >> 16));
        }
    } else {
        const float4* rp = (const float4*)((const float*)Cbase + c2_off + (size_t)v * EMBED);
#pragma unroll
        for (int i = 0; i < 16; ++i) {
            float4 r = rp[i];
            row[i*4 + 0] = r.x; row[i*4 + 1] = r.y;
            row[i*4 + 2] = r.z; row[i*4 + 3] = r.w;
        }
    }

    float res[BATCH];
#pragma unroll
    for (int b = 0; b < BATCH; ++b) {
        const float4* sp = (const float4*)(su + b * EMBED);
        float acc = 0.f;
#pragma unroll
        for (int e4 = 0; e4 < 16; ++e4) {
            float4 us = sp[e4];
            acc += row[e4*4+0]*us.x + row[e4*4+1]*us.y
                 + row[e4*4+2]*us.z + row[e4*4+3]*us.w;
        }
        res[b] = acc;
    }

    if (bf) {
        unsigned short* ob = (unsigned short*)out;
#pragma unroll
        for (int b = 0; b < BATCH; ++b) {
            __hip_bfloat16 h = __float2bfloat16(res[b]);
            ob[(size_t)b * VOCAB + v] = *(unsigned short*)&h;
        }
    } else {
        float* of = (float*)out;
#pragma unroll
        for (int b = 0; b < BATCH; ++b)
            of[(size_t)b * VOCAB + v] = res[b];
    }
}

extern "C" void kernel_launch(void* const* d_in, const int* in_sizes, int n_in,
                              void* d_out, int out_size, void* d_ws, size_t ws_size,
                              hipStream_t stream)
{
    const int*  stories = (const int*)d_in[0];   // [32,50,20] int32
    const int*  queries = (const int*)d_in[1];   // [32,20]    int32
    const void* A       = d_in[2];               // [100000,64]   f32 or bf16
    const void* C       = d_in[3];               // [3,100000,64] f32 or bf16
    const void* enc     = d_in[4];               // [20,64]       f32 or bf16

    float* u      = (float*)d_ws;                  // 32*64
    float* c_ws   = u + BATCH * EMBED;             // 32*50*64
    float* dotted = c_ws + BATCH * MEM * EMBED;    // 32*50

    k_query<<<BATCH, 64, 0, stream>>>(queries, A, enc, u);

    for (int hop = 0; hop < HOPS; ++hop) {
        size_t tin_off = (size_t)(hop - 1) * VOCAB * EMBED;   // element offset (hop>0)
        size_t tc_off  = (size_t)hop * VOCAB * EMBED;         // element offset
        k_hop1<<<BATCH * MEM, 64, 0, stream>>>(stories, A, C,
                                               tin_off, tc_off, hop == 0 ? 1 : 0,
                                               enc, u, c_ws, dotted);
        k_hop2<<<BATCH, 64, 0, stream>>>(dotted, c_ws, u);
    }

    k_out<<<(VOCAB + 255) / 256, 256, 0, stream>>>(u, C, enc, d_out);
}